// Round 6
// baseline (211.368 us; speedup 1.0000x reference)
//
#include <hip/hip_runtime.h>
#include <hip/hip_bf16.h>

// GroupLinear: out[t] = x[t] @ w[gid(t)].T
// T=8192, G=8, K=1024, N=2048; groups = contiguous token ranges (cum end-offs).
//
// R11 = 8-phase counted-vmcnt GEMM, derived from the m201/m248 template with a
// full stage/consume/overwrite timeline (R6/R9 failed on phase CONTENT):
//  - BM=BN=256, BK=64; 512 thr, 8 waves (2M x 4N), per-wave 128x64 C.
//  - A held IN REGISTERS per K-tile (16 ds_read_b128 at phase 0 only);
//    phases p=0..3 each compute n-frag p: 16 MFMA (8 m-frags x 2 ks).
//  - Rings: A 4 half-slots (2dbuf x 2half, 64KB), B 8 quarter-slots (64KB).
//    Stage schedule per tile t: p0:Bq0,Bq1(t+1) p1:Bq2,Bq3(t+1)
//    p2:Alo(t+2) p3:Ahi(t+2) + vmcnt(4) (= A(t+2)'s loads outstanding ->
//    tile t+1 fully landed; NEVER drains in the main loop).
//    WAR-safety: B(t+1)@p0(t) overwrites B(t-1) (last read p3(t-1),
//    barrier-separated); A(t+2)@p2(t) overwrites A(t) (last read p0(t)).
//  - 2 barriers/phase, setprio(1) around the 16-MFMA cluster (T5: phases give
//    waves role diversity), R9's fence discipline (correctness-proven).
//  - Grid (8,40)=320 blocks, bijective XCD swizzle (8x5x8); 128KB LDS,
//    1 block/CU; launch_bounds(512,2) -> 256 VGPR cap (est ~230).
//  - Fragment reads / XOR swizzle / C-layout / row-masking: verified R5 path.
//  cvt + fallback unchanged.

#define T_DIM 8192
#define G_DIM 8
#define K_DIM 1024
#define N_DIM 2048
#define MAX_PAIRS 40        // 32 m-tiles(256) + <=7 boundary dups, padded (%8==0)
#define NT (K_DIM / 64)     // 16 K-tiles

using short8  = __attribute__((ext_vector_type(8))) short;   // 8 bf16
using f32x4   = __attribute__((ext_vector_type(4))) float;
using ushort8 = __attribute__((ext_vector_type(8))) unsigned short;

typedef __attribute__((address_space(1))) void gvoid;  // global
typedef __attribute__((address_space(3))) void lvoid;  // LDS

#define FENCE() asm volatile("" ::: "memory")

// ---------------- fp32 -> bf16 convert (grid-stride, 2x unroll, nt loads) ---
__global__ __launch_bounds__(256) void cvt_kernel(const float* __restrict__ x,
                                                  const float* __restrict__ w,
                                                  ushort8* __restrict__ xb,
                                                  ushort8* __restrict__ wb,
                                                  int n8x, int n8tot) {
  const int stride = gridDim.x * blockDim.x;
  for (int i = blockIdx.x * blockDim.x + threadIdx.x; i < n8tot; i += 2 * stride) {
#pragma unroll
    for (int u = 0; u < 2; ++u) {
      const int idx = i + u * stride;
      if (idx >= n8tot) break;
      const f32x4* s; ushort8* d; int j;
      if (idx < n8x) { s = (const f32x4*)x; d = xb; j = idx; }
      else           { s = (const f32x4*)w; d = wb; j = idx - n8x; }
      f32x4 v0 = __builtin_nontemporal_load(&s[2 * j]);
      f32x4 v1 = __builtin_nontemporal_load(&s[2 * j + 1]);
      ushort8 o;
      o[0] = __builtin_bit_cast(unsigned short, __float2bfloat16(v0[0]));
      o[1] = __builtin_bit_cast(unsigned short, __float2bfloat16(v0[1]));
      o[2] = __builtin_bit_cast(unsigned short, __float2bfloat16(v0[2]));
      o[3] = __builtin_bit_cast(unsigned short, __float2bfloat16(v0[3]));
      o[4] = __builtin_bit_cast(unsigned short, __float2bfloat16(v1[0]));
      o[5] = __builtin_bit_cast(unsigned short, __float2bfloat16(v1[1]));
      o[6] = __builtin_bit_cast(unsigned short, __float2bfloat16(v1[2]));
      o[7] = __builtin_bit_cast(unsigned short, __float2bfloat16(v1[3]));
      d[j] = o;
    }
  }
}

// ---------------- grouped bf16 GEMM: 256x256, 8-phase counted pipeline ------
__global__ __launch_bounds__(512, 2) void grouped_gemm_kernel(
    const __hip_bfloat16* __restrict__ xb,
    const __hip_bfloat16* __restrict__ wb,
    const int* __restrict__ offs,
    float* __restrict__ out) {
  // ---- bijective XCD swizzle: 320 = 8 XCD x 5 pairs x 8 n-blocks.
  const int v  = blockIdx.y * 8 + blockIdx.x;    // grid (8,40)
  const int c  = v & 7;
  const int l  = v >> 3;                          // 0..39
  const int p  = c * 5 + (l % 5);                 // pair 0..39
  const int nb = l / 5;                           // n-block 0..7
  const int n0 = nb * 256;

  // ---- map pair p -> (expert g, 256-row m-tile) via prefix sum of spans
  int offv[G_DIM];
#pragma unroll
  for (int i = 0; i < G_DIM; ++i) offv[i] = offs[i];

  int g = -1, tile = 0, lo = 0, hi = 0, pre = 0;
#pragma unroll
  for (int gi = 0; gi < G_DIM; ++gi) {
    const int lb = gi ? offv[gi - 1] : 0;
    const int hb = offv[gi];
    const int t0 = lb >> 8;
    const int cnt = (hb > lb) ? (((hb + 255) >> 8) - t0) : 0;
    if (g < 0 && p < pre + cnt) { g = gi; tile = t0 + (p - pre); lo = lb; hi = hb; }
    pre += cnt;
  }
  if (g < 0) return;  // dead pair; uniform per block, before any barrier

  const int m0 = tile * 256;

  // A ring: 4 half-slots x (128x64) = 64KB; half h of tile t -> slot (t&1)*2+h.
  // B ring: 8 quarter-slots x (64x64) = 64KB; quarter q -> slot (t&1)*4+q.
  __shared__ __align__(16) __hip_bfloat16 Ar[4 * 128 * 64];
  __shared__ __align__(16) __hip_bfloat16 Br[8 * 64 * 64];

  const __hip_bfloat16* wg = wb + (size_t)g * N_DIM * K_DIM;

  const int lane = threadIdx.x & 63;
  const int wid  = threadIdx.x >> 6;   // 0..7
  const int wm   = wid >> 2;           // 0..1 -> m offset 128
  const int wn   = wid & 3;            // 0..3 -> n offset 64

  // staging: chunk = 8 rows x 64 cols = 1KB; lane -> chunk base + lane*16B.
  // row&7 == srow -> XOR swizzle permutes the GLOBAL column block (rule 21).
  const int srow = lane >> 3;
  const int scol = ((lane & 7) ^ srow) * 8;

  // A half (16KB = 16 chunks): 2 loads/thread. B quarter (8KB): 1 load/thread.
  auto stageA = [&](int tt, int h) {
    const int slot = (tt & 1) * 2 + h;
#pragma unroll
    for (int i = 0; i < 2; ++i) {
      const int ch = wid * 2 + i;  // 0..15
      const __hip_bfloat16* src =
          xb + (size_t)(m0 + h * 128 + ch * 8 + srow) * K_DIM + tt * 64 + scol;
      __builtin_amdgcn_global_load_lds(
          (gvoid*)src, (lvoid*)(Ar + slot * 8192 + ch * 512 + lane * 8), 16, 0, 0);
    }
  };
  auto stageB = [&](int tt, int q) {
    const int slot = (tt & 1) * 4 + q;
    const __hip_bfloat16* src =
        wg + (size_t)(n0 + q * 64 + wid * 8 + srow) * K_DIM + tt * 64 + scol;
    __builtin_amdgcn_global_load_lds(
        (gvoid*)src, (lvoid*)(Br + slot * 4096 + wid * 512 + lane * 8), 16, 0, 0);
  };

  f32x4 acc[8][4] = {};  // [mf][nf]

  // ---- prologue: tile0 (A 4 + B 4 loads) + A(1) (4); vmcnt(4)=tile0 landed.
  stageA(0, 0); stageA(0, 1);
  stageB(0, 0); stageB(0, 1); stageB(0, 2); stageB(0, 3);
  stageA(1, 0); stageA(1, 1);
  asm volatile("s_waitcnt vmcnt(4)" ::: "memory");
  __builtin_amdgcn_s_barrier();
  FENCE();

  for (int t = 0; t < NT; ++t) {
    const int abase = ((t & 1) * 2 + wm) * 8192;  // wave's A half slot
    const int bbase = ((t & 1) * 4 + wn) * 4096;  // wave's B quarter slot
    short8 a[8][2];

#pragma unroll
    for (int ph = 0; ph < 4; ++ph) {
      // ---- ds_reads for this phase (pre-barrier; compiler orders lgkm)
      if (ph == 0) {
#pragma unroll
        for (int mf = 0; mf < 8; ++mf)
#pragma unroll
          for (int ks = 0; ks < 2; ++ks) {
            const int off = (((ks * 4 + (lane >> 4)) ^ (lane & 7)) * 8);
            a[mf][ks] = *reinterpret_cast<const short8*>(
                Ar + abase + (mf * 16 + (lane & 15)) * 64 + off);
          }
      }
      short8 b0, b1;
      {
        const int row = ph * 16 + (lane & 15);
        const int o0  = (((lane >> 4) ^ (lane & 7)) * 8);
        const int o1  = (((4 + (lane >> 4)) ^ (lane & 7)) * 8);
        b0 = *reinterpret_cast<const short8*>(Br + bbase + row * 64 + o0);
        b1 = *reinterpret_cast<const short8*>(Br + bbase + row * 64 + o1);
      }

      // ---- stage schedule (2 loads/thread/phase; WAR-safe per timeline)
      if (ph == 0 && t + 1 < NT) { stageB(t + 1, 0); stageB(t + 1, 1); }
      if (ph == 1 && t + 1 < NT) { stageB(t + 1, 2); stageB(t + 1, 3); }
      if (ph == 2 && t + 2 < NT) { stageA(t + 2, 0); }
      if (ph == 3) {
        if (t + 2 < NT) {
          stageA(t + 2, 1);
          // A(t+2)'s 4 loads may stay in flight; tile t+1 has landed
          asm volatile("s_waitcnt vmcnt(4)" ::: "memory");
        } else if (t + 1 < NT) {
          asm volatile("s_waitcnt vmcnt(0)" ::: "memory");  // tail drain
        }
      }

      FENCE();
      __builtin_amdgcn_s_barrier();
      FENCE();

      __builtin_amdgcn_s_setprio(1);
#pragma unroll
      for (int mf = 0; mf < 8; ++mf) {
        acc[mf][ph] = __builtin_amdgcn_mfma_f32_16x16x32_bf16(
            a[mf][0], b0, acc[mf][ph], 0, 0, 0);
        acc[mf][ph] = __builtin_amdgcn_mfma_f32_16x16x32_bf16(
            a[mf][1], b1, acc[mf][ph], 0, 0, 0);
      }
      __builtin_amdgcn_s_setprio(0);

      FENCE();
      __builtin_amdgcn_s_barrier();
      FENCE();
    }
  }

  // ---- epilogue: C/D layout col=lane&15, row=(lane>>4)*4+reg [m89-verified];
  // store only rows in [lo,hi) — boundary tiles written disjointly per expert.
  const int quad = lane >> 4;
#pragma unroll
  for (int mf = 0; mf < 8; ++mf) {
    const int rbase = m0 + wm * 128 + mf * 16 + quad * 4;
#pragma unroll
    for (int r = 0; r < 4; ++r) {
      const int row = rbase + r;
      if (row < lo || row >= hi) continue;
#pragma unroll
      for (int nf = 0; nf < 4; ++nf) {
        const int col = n0 + wn * 64 + nf * 16 + (lane & 15);
        out[(size_t)row * N_DIM + col] = acc[mf][nf][r];
      }
    }
  }
}

// ---------------- fp32 fallback (only if d_ws < 48 MB; correctness-only) ----
__global__ __launch_bounds__(256) void fallback_kernel(
    const float* __restrict__ x, const float* __restrict__ w,
    const int* __restrict__ offs, float* __restrict__ out) {
  __shared__ float xs[K_DIM];
  const int t = blockIdx.y;
  int g = 0;
  while (g < G_DIM - 1 && offs[g] <= t) ++g;
  for (int i = threadIdx.x; i < K_DIM; i += blockDim.x)
    xs[i] = x[(size_t)t * K_DIM + i];
  __syncthreads();
  const int n = blockIdx.x * blockDim.x + threadIdx.x;
  const float* wr = w + ((size_t)g * N_DIM + n) * K_DIM;
  float s = 0.f;
  for (int k = 0; k < K_DIM; ++k) s += xs[k] * wr[k];
  out[(size_t)t * N_DIM + n] = s;
}

extern "C" void kernel_launch(void* const* d_in, const int* in_sizes, int n_in,
                              void* d_out, int out_size, void* d_ws, size_t ws_size,
                              hipStream_t stream) {
  const float* x    = (const float*)d_in[0];
  const float* w    = (const float*)d_in[1];
  const int*   offs = (const int*)d_in[2];
  float*       out  = (float*)d_out;

  const size_t x_elems = (size_t)T_DIM * K_DIM;            // 8.39M
  const size_t w_elems = (size_t)G_DIM * N_DIM * K_DIM;    // 16.78M
  const size_t need    = (x_elems + w_elems) * sizeof(__hip_bfloat16);  // 48 MiB

  if (ws_size < need) {
    fallback_kernel<<<dim3(N_DIM / 256, T_DIM), 256, 0, stream>>>(x, w, offs, out);
    return;
  }

  __hip_bfloat16* xb = (__hip_bfloat16*)d_ws;
  __hip_bfloat16* wb = xb + x_elems;

  const int n8x   = (int)(x_elems / 8);              // 1,048,576
  const int n8tot = (int)((x_elems + w_elems) / 8);  // 3,145,728
  cvt_kernel<<<4096, 256, 0, stream>>>(x, w, (ushort8*)xb, (ushort8*)wb,
                                       n8x, n8tot);

  grouped_gemm_kernel<<<dim3(8, MAX_PAIRS), 512, 0, stream>>>(
      xb, wb, offs, out);
}